// Round 11
// baseline (269.192 us; speedup 1.0000x reference)
//
#include <hip/hip_runtime.h>
#include <math.h>

// VQ-VAE quantize: z [8,4096,512] f32, embed_w [1024,512] f32
// out = concat(z_q, diff, ind-as-f32)
//
// bf16 split-precision MFMA:  dot ~= zhi*ehi + zhi*elo + zlo*ehi
// score = ||e||^2 - 2*dot  (row-constant ||z||^2 dropped; argmin invariant)
// gemm: 256x128 tile, 8 waves, 3-deep LDS ring (144 KB, 1 block/CU), k-tile
// split into 3 barrier-separated fine phases (hh/hl/lh). RACE FIXES vs r10:
// (1) last tile waits vmcnt(0); (2) phase-A frag reads AFTER the barrier
// (vmcnt is per-wave; only the barrier proves all waves' DMA landed).

#define D_DIM   512
#define K_CODES 1024
#define N_TOK   32768

#define BM 256
#define BN 128
#define NKT 16            // 512 / 32 bf16-cols per k-tile
#define BUFU 24576        // ushorts per ring buffer (48 KB)

typedef __attribute__((ext_vector_type(8))) short bf16x8;
typedef __attribute__((ext_vector_type(4))) float f32x4;

__device__ __forceinline__ unsigned short bf16_rne(float f) {
    unsigned int u = __float_as_uint(f);
    return (unsigned short)((u + 0x7FFFu + ((u >> 16) & 1u)) >> 16);
}
__device__ __forceinline__ float bf16_to_f32(unsigned short b) {
    return __uint_as_float(((unsigned int)b) << 16);
}

#define GLOAD16(gp, lp)                                                        \
    __builtin_amdgcn_global_load_lds(                                          \
        (const __attribute__((address_space(1))) void*)(gp),                   \
        (__attribute__((address_space(3))) void*)(lp), 16, 0, 0)

#define SB0 __builtin_amdgcn_sched_barrier(0)

// ---------------- z -> zhi/zlo bf16 planes --------------------------------
__global__ __launch_bounds__(256) void vq_zsplit(const float* __restrict__ z,
                                                 unsigned short* __restrict__ zhi,
                                                 unsigned short* __restrict__ zlo) {
    const int tid = blockIdx.x * 256 + threadIdx.x;   // grid 2048
    const float4* z4 = (const float4*)z;
    ushort4* h4 = (ushort4*)zhi;
    ushort4* l4 = (ushort4*)zlo;
#pragma unroll
    for (int g = 0; g < 8; ++g) {
        const size_t i = (size_t)g * 524288 + tid;
        float4 v = z4[i];
        float f[4] = {v.x, v.y, v.z, v.w};
        unsigned short hb[4], lb[4];
#pragma unroll
        for (int j = 0; j < 4; ++j) {
            hb[j] = bf16_rne(f[j]);
            lb[j] = bf16_rne(f[j] - bf16_to_f32(hb[j]));
        }
        h4[i] = make_ushort4(hb[0], hb[1], hb[2], hb[3]);
        l4[i] = make_ushort4(lb[0], lb[1], lb[2], lb[3]);
    }
}

// ---------------- ew -> ehi/elo bf16 + e2 ---------------------------------
__global__ __launch_bounds__(256) void vq_prep(const float* __restrict__ ew,
                                               unsigned short* __restrict__ ehi,
                                               unsigned short* __restrict__ elo,
                                               float* __restrict__ e2) {
    const int wv = threadIdx.x >> 6, lane = threadIdx.x & 63;
    const int code = blockIdx.x * 4 + wv;          // grid 256
    const float* row = ew + (size_t)code * D_DIM;
    float s = 0.0f;
#pragma unroll
    for (int h = 0; h < 2; ++h) {
        const int c = h * 256 + lane * 4;
        float4 v = *(const float4*)(row + c);
        float f[4] = {v.x, v.y, v.z, v.w};
        unsigned short hb[4], lb[4];
#pragma unroll
        for (int j = 0; j < 4; ++j) {
            s = fmaf(f[j], f[j], s);
            hb[j] = bf16_rne(f[j]);
            lb[j] = bf16_rne(f[j] - bf16_to_f32(hb[j]));
        }
        *(ushort4*)(ehi + (size_t)code * D_DIM + c) = make_ushort4(hb[0], hb[1], hb[2], hb[3]);
        *(ushort4*)(elo + (size_t)code * D_DIM + c) = make_ushort4(lb[0], lb[1], lb[2], lb[3]);
    }
#pragma unroll
    for (int off = 32; off > 0; off >>= 1) s += __shfl_xor(s, off, 64);
    if (lane == 0) e2[code] = s;
}

// ---------------- split-GEMM + per-tile argmin (3-phase ring) -------------
__global__ __launch_bounds__(512, 2) void vq_gemm(
    const unsigned short* __restrict__ zhi, const unsigned short* __restrict__ zlo,
    const unsigned short* __restrict__ ehi, const unsigned short* __restrict__ elo,
    const float* __restrict__ e2, float* __restrict__ pv, float* __restrict__ pif) {
    // 3 ring buffers x 48 KB = 144 KB. Per buffer (ushort offsets):
    //   AHI 0 [4 kchunk][256 row]x8 ; ALO 8192 ; BHI 16384 [4][128]x8 ; BLO 20480
    __shared__ __align__(16) unsigned short lds[3 * BUFU];
    const int AHI = 0, ALO = 8192, BHI = 16384, BLO = 20480;

    const int t = threadIdx.x, lane = t & 63, wv = t >> 6;
    // XCD-contiguous swizzle: 1024 wgs, 8 XCDs, 128 each; ntile innermost
    const int b  = blockIdx.x;
    const int wg = (b & 7) * 128 + (b >> 3);
    const int mtile = wg >> 3, ntile = wg & 7;
    const int row0 = mtile * BM;
    const int c0g  = ntile * BN;

    // staging coords (6 gloads/thread/tile: 4 A-plane, 2 B-plane)
    const int acA = t >> 8;        // 0..1 (A kchunk low bit)
    const int arr = t & 255;       // A row in tile
    const int bcc = t >> 7;        // 0..3 (B kchunk)
    const int brr = t & 127;       // B row (code) in tile

    const int wr = wv >> 1, wc = wv & 1;       // 4x2 wave grid (64x64 out each)
    const int lm = lane & 15, lk = lane >> 4;

    f32x4 acc[4][4];
    const f32x4 zero4 = {0.f, 0.f, 0.f, 0.f};
#pragma unroll
    for (int i = 0; i < 4; ++i)
#pragma unroll
        for (int j = 0; j < 4; ++j) acc[i][j] = zero4;

    auto stage = [&](int kt, int bo) {
        const int ko = kt * 32;
#pragma unroll
        for (int q = 0; q < 2; ++q) {
            const size_t zo = (size_t)(row0 + arr) * D_DIM + ko + (q * 2 + acA) * 8;
            const int sl = (q * 512 + t) * 8;
            GLOAD16(zhi + zo, &lds[bo + AHI + sl]);
            GLOAD16(zlo + zo, &lds[bo + ALO + sl]);
        }
        const size_t eo = (size_t)(c0g + brr) * D_DIM + ko + bcc * 8;
        const int slb = t * 8;
        GLOAD16(ehi + eo, &lds[bo + BHI + slb]);
        GLOAD16(elo + eo, &lds[bo + BLO + slb]);
    };

    // prologue: two tiles in flight (12 gloads/thread outstanding)
    stage(0, 0);
    stage(1, BUFU);

    int boA = 0, boB = BUFU, boC = 2 * BUFU;   // buf(t), buf(t+1), buf(t+2)
    for (int kt = 0; kt < NKT; ++kt) {
        bf16x8 ah[4], bh[4], bl[4], al[4];
        // ======== Phase A: vmcnt | barrier | reads(ah,bh) | stage | hh ======
        if (kt < NKT - 1) asm volatile("s_waitcnt vmcnt(6)" ::: "memory");
        else              asm volatile("s_waitcnt vmcnt(0)" ::: "memory");
        __builtin_amdgcn_s_barrier();          // ALL waves' tile-kt DMA landed
        SB0;
#pragma unroll
        for (int mi = 0; mi < 4; ++mi)
            ah[mi] = *(const bf16x8*)&lds[boA + AHI + (lk * 256 + wr * 64 + mi * 16 + lm) * 8];
#pragma unroll
        for (int nj = 0; nj < 4; ++nj)
            bh[nj] = *(const bf16x8*)&lds[boA + BHI + (lk * 128 + wc * 64 + nj * 16 + lm) * 8];
        SB0;                                    // stage may not hoist above barrier
        if (kt + 2 < NKT) stage(kt + 2, boC);   // boC reads retired @ kt-1 end
        asm volatile("s_waitcnt lgkmcnt(0)" ::: "memory");
        SB0;
        __builtin_amdgcn_s_setprio(1);
#pragma unroll
        for (int mi = 0; mi < 4; ++mi)
#pragma unroll
            for (int nj = 0; nj < 4; ++nj)
                acc[mi][nj] = __builtin_amdgcn_mfma_f32_16x16x32_bf16(
                    ah[mi], bh[nj], acc[mi][nj], 0, 0, 0);
        __builtin_amdgcn_s_setprio(0);
        SB0;
        // ======== Phase B: reads(bl) | barrier | hl MFMAs ========
#pragma unroll
        for (int nj = 0; nj < 4; ++nj)
            bl[nj] = *(const bf16x8*)&lds[boA + BLO + (lk * 128 + wc * 64 + nj * 16 + lm) * 8];
        SB0;
        __builtin_amdgcn_s_barrier();
        asm volatile("s_waitcnt lgkmcnt(0)" ::: "memory");
        SB0;
        __builtin_amdgcn_s_setprio(1);
#pragma unroll
        for (int mi = 0; mi < 4; ++mi)
#pragma unroll
            for (int nj = 0; nj < 4; ++nj)
                acc[mi][nj] = __builtin_amdgcn_mfma_f32_16x16x32_bf16(
                    ah[mi], bl[nj], acc[mi][nj], 0, 0, 0);
        __builtin_amdgcn_s_setprio(0);
        SB0;
        // ======== Phase C: reads(al) | barrier | lh MFMAs ========
#pragma unroll
        for (int mi = 0; mi < 4; ++mi)
            al[mi] = *(const bf16x8*)&lds[boA + ALO + (lk * 256 + wr * 64 + mi * 16 + lm) * 8];
        SB0;
        __builtin_amdgcn_s_barrier();
        asm volatile("s_waitcnt lgkmcnt(0)" ::: "memory");
        SB0;
        __builtin_amdgcn_s_setprio(1);
#pragma unroll
        for (int mi = 0; mi < 4; ++mi)
#pragma unroll
            for (int nj = 0; nj < 4; ++nj)
                acc[mi][nj] = __builtin_amdgcn_mfma_f32_16x16x32_bf16(
                    al[mi], bh[nj], acc[mi][nj], 0, 0, 0);
        __builtin_amdgcn_s_setprio(0);
        SB0;
        const int tmp = boA; boA = boB; boB = boC; boC = tmp;
    }

    // ---- epilogue: score + per-row argmin over this 128-code tile ----
    // D mapping (16x16x32 bf16): col=lane&15 (code), row=(lane>>4)*4+reg (z-row)
    float best[16], bidx[16];
#pragma unroll
    for (int i = 0; i < 16; ++i) { best[i] = INFINITY; bidx[i] = 0.f; }
#pragma unroll
    for (int nj = 0; nj < 4; ++nj) {
        const int cloc = wc * 64 + nj * 16 + lm;
        const float e2v = e2[c0g + cloc];
#pragma unroll
        for (int mi = 0; mi < 4; ++mi)
#pragma unroll
            for (int r = 0; r < 4; ++r) {
                const float sc = fmaf(-2.0f, acc[mi][nj][r], e2v);
                const int bi = mi * 4 + r;
                if (sc < best[bi]) { best[bi] = sc; bidx[bi] = (float)(c0g + cloc); }
            }
    }
#pragma unroll
    for (int off = 1; off < 16; off <<= 1) {
#pragma unroll
        for (int bi = 0; bi < 16; ++bi) {
            float v2 = __shfl_xor(best[bi], off, 64);
            float i2 = __shfl_xor(bidx[bi], off, 64);
            if (v2 < best[bi] || (v2 == best[bi] && i2 < bidx[bi])) {
                best[bi] = v2; bidx[bi] = i2;
            }
        }
    }
    __syncthreads();                 // LDS free; reuse for cross-wave reduce
    float* sv = (float*)lds;         // [2][256]
    float* si = sv + 512;
    if (lm == 0) {
#pragma unroll
        for (int mi = 0; mi < 4; ++mi)
#pragma unroll
            for (int r = 0; r < 4; ++r) {
                const int rl = wr * 64 + mi * 16 + lk * 4 + r;
                sv[wc * 256 + rl] = best[mi * 4 + r];
                si[wc * 256 + rl] = bidx[mi * 4 + r];
            }
    }
    __syncthreads();
    if (t < 256) {
        float v0 = sv[t], i0 = si[t];
        float v1 = sv[256 + t], i1 = si[256 + t];
        if (v1 < v0 || (v1 == v0 && i1 < i0)) { v0 = v1; i0 = i1; }
        pv [(size_t)ntile * N_TOK + row0 + t] = v0;
        pif[(size_t)ntile * N_TOK + row0 + t] = i0;
    }
}

// ---------------- outputs: fused 8-tile argmin + z_q, diff, ind -----------
__global__ __launch_bounds__(256) void vq_out_kernel(
    const float* __restrict__ z, const float* __restrict__ ew,
    const float* __restrict__ pv, const float* __restrict__ pif,
    float* __restrict__ indf, float* __restrict__ zq, float* __restrict__ diff) {
    const int w    = threadIdx.x >> 6;
    const int lane = threadIdx.x & 63;
    const int row  = blockIdx.x * 4 + w;

    // reduce the 8 n-tile partials (ascending -> first-min semantics)
    float v = INFINITY, ix = 0.f;
    if (lane < 8) {
        v  = pv [(size_t)lane * N_TOK + row];
        ix = pif[(size_t)lane * N_TOK + row];
    }
#pragma unroll
    for (int off = 1; off < 8; off <<= 1) {
        float v2 = __shfl_xor(v, off, 64);
        float i2 = __shfl_xor(ix, off, 64);
        if (v2 < v || (v2 == v && i2 < ix)) { v = v2; ix = i2; }
    }
    const float ixb = __shfl(ix, 0, 64);
    const int c = (int)ixb;
    if (lane == 0) indf[row] = ixb;

    const float4* z4 = (const float4*)&z[(size_t)row * D_DIM];
    const float4* e4 = (const float4*)&ew[(size_t)c * D_DIM];
    float4* q4 = (float4*)&zq[(size_t)row * D_DIM];
    float4* d4 = (float4*)&diff[(size_t)row * D_DIM];

#pragma unroll
    for (int vv = 0; vv < 2; ++vv) {
        const int i = vv * 64 + lane;
        const float4 zv = z4[i];
        const float4 ev = e4[i];
        float4 qv, dv;
        float ax = ev.x - zv.x, ay = ev.y - zv.y, az = ev.z - zv.z, aw = ev.w - zv.w;
        qv.x = zv.x + ax; qv.y = zv.y + ay; qv.z = zv.z + az; qv.w = zv.w + aw;
        dv.x = 0.5f * (ax * ax); dv.y = 0.5f * (ay * ay);
        dv.z = 0.5f * (az * az); dv.w = 0.5f * (aw * aw);
        q4[i] = qv;
        d4[i] = dv;
    }
}

extern "C" void kernel_launch(void* const* d_in, const int* in_sizes, int n_in,
                              void* d_out, int out_size, void* d_ws, size_t ws_size,
                              hipStream_t stream) {
    const float* z  = (const float*)d_in[0];
    const float* ew = (const float*)d_in[1];
    float* out  = (float*)d_out;
    float* zq   = out;
    float* diff = out + (size_t)N_TOK * D_DIM;
    float* indf = out + (size_t)2 * N_TOK * D_DIM;

    // scratch: ehi/elo/e2 in zq region (gemm reads them; out-kernel writes zq
    // only after); zhi/zlo in diff region; pv/pif in d_ws.
    char* s0 = (char*)d_out;
    unsigned short* ehi = (unsigned short*)(s0);                   // 1 MB
    unsigned short* elo = (unsigned short*)(s0 + (1u << 20));      // 1 MB
    float* e2  = (float*)(s0 + (2u << 20));                        // 4 KB
    unsigned short* zhi = (unsigned short*)diff;                   // 32 MB
    unsigned short* zlo = zhi + (size_t)N_TOK * D_DIM;             // 32 MB
    float* pv  = (float*)d_ws;                                     // 1 MB
    float* pif = (float*)d_ws + (size_t)8 * N_TOK;                 // 1 MB

    hipLaunchKernelGGL(vq_zsplit, dim3(2048),        dim3(256), 0, stream, z, zhi, zlo);
    hipLaunchKernelGGL(vq_prep,   dim3(K_CODES / 4), dim3(256), 0, stream, ew, ehi, elo, e2);
    hipLaunchKernelGGL(vq_gemm,   dim3(N_TOK / BM * 8), dim3(512), 0, stream,
                       zhi, zlo, ehi, elo, e2, pv, pif);
    hipLaunchKernelGGL(vq_out_kernel, dim3(N_TOK / 4), dim3(256), 0, stream,
                       z, ew, pv, pif, indf, zq, diff);
}

// Round 13
// 252.302 us; speedup vs baseline: 1.0669x; 1.0669x over previous
//
#include <hip/hip_runtime.h>
#include <math.h>

// VQ-VAE quantize: z [8,4096,512] f32, embed_w [1024,512] f32
// out = concat(z_q, diff, ind-as-f32)
//
// bf16 split-precision MFMA:  dot ~= zhi*ehi + zhi*elo + zlo*ehi
// score = ||e||^2 - 2*dot  (row-constant ||z||^2 dropped; argmin invariant)
// gemm v13: A-planes (z) staged via global_load_lds into a 16KB buffer
// (32KB dbuf -> 4 blocks/CU); B-planes (e, 2MB, L2-resident) loaded DIRECTLY
// into registers with per-lane frag addresses -> LDS reads halve, one
// __syncthreads per k-tile (stage issued after it; bottom barrier redundant
// since ds_reads retire via lgkmcnt before each wave reaches the next top
// barrier). JIT frag reads bound live regs.

#define D_DIM   512
#define K_CODES 1024
#define N_TOK   32768

#define BM 128
#define BN 128
#define NKT 16            // 512 / 32 bf16-cols per k-tile
#define BUFU 8192         // ushorts per LDS buffer (16 KB): AHI 4096 | ALO 4096

typedef __attribute__((ext_vector_type(8))) short bf16x8;
typedef __attribute__((ext_vector_type(4))) float f32x4;

__device__ __forceinline__ unsigned short bf16_rne(float f) {
    unsigned int u = __float_as_uint(f);
    return (unsigned short)((u + 0x7FFFu + ((u >> 16) & 1u)) >> 16);
}
__device__ __forceinline__ float bf16_to_f32(unsigned short b) {
    return __uint_as_float(((unsigned int)b) << 16);
}

#define GLOAD16(gp, lp)                                                        \
    __builtin_amdgcn_global_load_lds(                                          \
        (const __attribute__((address_space(1))) void*)(gp),                   \
        (__attribute__((address_space(3))) void*)(lp), 16, 0, 0)

#define SB0 __builtin_amdgcn_sched_barrier(0)

// ---------------- z -> zhi/zlo bf16 planes --------------------------------
__global__ __launch_bounds__(256) void vq_zsplit(const float* __restrict__ z,
                                                 unsigned short* __restrict__ zhi,
                                                 unsigned short* __restrict__ zlo) {
    const int tid = blockIdx.x * 256 + threadIdx.x;   // grid 2048
    const float4* z4 = (const float4*)z;
    ushort4* h4 = (ushort4*)zhi;
    ushort4* l4 = (ushort4*)zlo;
#pragma unroll
    for (int g = 0; g < 8; ++g) {
        const size_t i = (size_t)g * 524288 + tid;
        float4 v = z4[i];
        float f[4] = {v.x, v.y, v.z, v.w};
        unsigned short hb[4], lb[4];
#pragma unroll
        for (int j = 0; j < 4; ++j) {
            hb[j] = bf16_rne(f[j]);
            lb[j] = bf16_rne(f[j] - bf16_to_f32(hb[j]));
        }
        h4[i] = make_ushort4(hb[0], hb[1], hb[2], hb[3]);
        l4[i] = make_ushort4(lb[0], lb[1], lb[2], lb[3]);
    }
}

// ---------------- ew -> ehi/elo bf16 + e2 ---------------------------------
__global__ __launch_bounds__(256) void vq_prep(const float* __restrict__ ew,
                                               unsigned short* __restrict__ ehi,
                                               unsigned short* __restrict__ elo,
                                               float* __restrict__ e2) {
    const int wv = threadIdx.x >> 6, lane = threadIdx.x & 63;
    const int code = blockIdx.x * 4 + wv;          // grid 256
    const float* row = ew + (size_t)code * D_DIM;
    float s = 0.0f;
#pragma unroll
    for (int h = 0; h < 2; ++h) {
        const int c = h * 256 + lane * 4;
        float4 v = *(const float4*)(row + c);
        float f[4] = {v.x, v.y, v.z, v.w};
        unsigned short hb[4], lb[4];
#pragma unroll
        for (int j = 0; j < 4; ++j) {
            s = fmaf(f[j], f[j], s);
            hb[j] = bf16_rne(f[j]);
            lb[j] = bf16_rne(f[j] - bf16_to_f32(hb[j]));
        }
        *(ushort4*)(ehi + (size_t)code * D_DIM + c) = make_ushort4(hb[0], hb[1], hb[2], hb[3]);
        *(ushort4*)(elo + (size_t)code * D_DIM + c) = make_ushort4(lb[0], lb[1], lb[2], lb[3]);
    }
#pragma unroll
    for (int off = 32; off > 0; off >>= 1) s += __shfl_xor(s, off, 64);
    if (lane == 0) e2[code] = s;
}

// ---------------- split-GEMM + per-tile argmin (B-from-L2) ----------------
__global__ __launch_bounds__(256, 4) void vq_gemm(
    const unsigned short* __restrict__ zhi, const unsigned short* __restrict__ zlo,
    const unsigned short* __restrict__ ehi, const unsigned short* __restrict__ elo,
    const float* __restrict__ e2, float* __restrict__ pv, float* __restrict__ pif) {
    // 2 buffers x 16 KB (A planes only): AHI [4 kchunk][128 row]x16B, ALO same
    __shared__ __align__(16) unsigned short lds[2 * BUFU];
    const int AHI = 0, ALO = 4096;

    const int t = threadIdx.x, lane = t & 63, wv = t >> 6;
    // XCD-contiguous swizzle: 2048 wgs, 8 XCDs, 256 each; ntile innermost
    const int b  = blockIdx.x;
    const int wg = (b & 7) * 256 + (b >> 3);
    const int mtile = wg >> 3, ntile = wg & 7;
    const int row0 = mtile * BM;
    const int c0g  = ntile * BN;

    // A staging: 2 slots/thread/plane; slot s=q*256+t -> kchunk s>>7, row s&127
    const int c_0 = t >> 7,        r_0 = t & 127;
    const int c_1 = 2 + (t >> 7),  r_1 = t & 127;
    const size_t zo0 = (size_t)(row0 + r_0) * D_DIM + c_0 * 8;
    const size_t zo1 = (size_t)(row0 + r_1) * D_DIM + c_1 * 8;
    const int sl0 = t * 8;
    const int sl1 = (256 + t) * 8;

    const int wr = wv >> 1, wc = wv & 1;
    const int lm = lane & 15, lk = lane >> 4;

    // per-lane B row base (code row for this lane's frag column)
    const size_t bbase = (size_t)(c0g + wc * 64 + lm) * D_DIM + lk * 8;
    const unsigned short* __restrict__ bh_p = ehi + bbase;
    const unsigned short* __restrict__ bl_p = elo + bbase;

    f32x4 acc[4][4];
    const f32x4 zero4 = {0.f, 0.f, 0.f, 0.f};
#pragma unroll
    for (int i = 0; i < 4; ++i)
#pragma unroll
        for (int j = 0; j < 4; ++j) acc[i][j] = zero4;

    auto stage = [&](int kt, int bufo) {
        const int ko = kt * 32;
        GLOAD16(zhi + zo0 + ko, &lds[bufo + AHI + sl0]);
        GLOAD16(zhi + zo1 + ko, &lds[bufo + AHI + sl1]);
        GLOAD16(zlo + zo0 + ko, &lds[bufo + ALO + sl0]);
        GLOAD16(zlo + zo1 + ko, &lds[bufo + ALO + sl1]);
    };

    stage(0, 0);
    for (int kt = 0; kt < NKT; ++kt) {
        const int bufo = (kt & 1) * BUFU;
        __syncthreads();                   // vmcnt(0): tile-kt A-DMA landed, all waves
        SB0;                               // stage below must not hoist above
        if (kt + 1 < NKT) stage(kt + 1, bufo ^ BUFU);

        // JIT 3-phase compute (bounds live regs; B straight from L2)
        bf16x8 ah[4], bh[4];
#pragma unroll
        for (int mi = 0; mi < 4; ++mi)
            ah[mi] = *(const bf16x8*)&lds[bufo + AHI + (lk * 128 + wr * 64 + mi * 16 + lm) * 8];
#pragma unroll
        for (int nj = 0; nj < 4; ++nj)
            bh[nj] = *(const bf16x8*)(bh_p + nj * (16 * D_DIM) + kt * 32);
        __builtin_amdgcn_s_setprio(1);
#pragma unroll
        for (int mi = 0; mi < 4; ++mi)
#pragma unroll
            for (int nj = 0; nj < 4; ++nj)
                acc[mi][nj] = __builtin_amdgcn_mfma_f32_16x16x32_bf16(
                    ah[mi], bh[nj], acc[mi][nj], 0, 0, 0);
        {
            bf16x8 bl[4];
#pragma unroll
            for (int nj = 0; nj < 4; ++nj)
                bl[nj] = *(const bf16x8*)(bl_p + nj * (16 * D_DIM) + kt * 32);
#pragma unroll
            for (int mi = 0; mi < 4; ++mi)
#pragma unroll
                for (int nj = 0; nj < 4; ++nj)
                    acc[mi][nj] = __builtin_amdgcn_mfma_f32_16x16x32_bf16(
                        ah[mi], bl[nj], acc[mi][nj], 0, 0, 0);
        }
        {
            bf16x8 al[4];
#pragma unroll
            for (int mi = 0; mi < 4; ++mi)
                al[mi] = *(const bf16x8*)&lds[bufo + ALO + (lk * 128 + wr * 64 + mi * 16 + lm) * 8];
#pragma unroll
            for (int mi = 0; mi < 4; ++mi)
#pragma unroll
                for (int nj = 0; nj < 4; ++nj)
                    acc[mi][nj] = __builtin_amdgcn_mfma_f32_16x16x32_bf16(
                        al[mi], bh[nj], acc[mi][nj], 0, 0, 0);
        }
        __builtin_amdgcn_s_setprio(0);
        // no bottom barrier: each wave's ds_reads retired (lgkmcnt) before its
        // MFMAs; next iteration's __syncthreads orders restage vs all waves.
    }

    // ---- epilogue: score + per-row argmin over this 128-code tile ----
    // D mapping (16x16x32 bf16): col=lane&15 (code), row=(lane>>4)*4+reg (z-row)
    float best[16], bidx[16];
#pragma unroll
    for (int i = 0; i < 16; ++i) { best[i] = INFINITY; bidx[i] = 0.f; }
#pragma unroll
    for (int nj = 0; nj < 4; ++nj) {
        const int cloc = wc * 64 + nj * 16 + lm;
        const float e2v = e2[c0g + cloc];
#pragma unroll
        for (int mi = 0; mi < 4; ++mi)
#pragma unroll
            for (int r = 0; r < 4; ++r) {
                const float sc = fmaf(-2.0f, acc[mi][nj][r], e2v);
                const int bi = mi * 4 + r;
                if (sc < best[bi]) { best[bi] = sc; bidx[bi] = (float)(c0g + cloc); }
            }
    }
#pragma unroll
    for (int off = 1; off < 16; off <<= 1) {
#pragma unroll
        for (int bi = 0; bi < 16; ++bi) {
            float v2 = __shfl_xor(best[bi], off, 64);
            float i2 = __shfl_xor(bidx[bi], off, 64);
            if (v2 < best[bi] || (v2 == best[bi] && i2 < bidx[bi])) {
                best[bi] = v2; bidx[bi] = i2;
            }
        }
    }
    __syncthreads();                 // LDS free; reuse for cross-wave reduce
    float* sv = (float*)lds;         // [2][128]
    float* si = sv + 256;
    if (lm == 0) {
#pragma unroll
        for (int mi = 0; mi < 4; ++mi)
#pragma unroll
            for (int r = 0; r < 4; ++r) {
                const int rl = wr * 64 + mi * 16 + lk * 4 + r;
                sv[wc * 128 + rl] = best[mi * 4 + r];
                si[wc * 128 + rl] = bidx[mi * 4 + r];
            }
    }
    __syncthreads();
    if (t < 128) {
        float v0 = sv[t], i0 = si[t];
        float v1 = sv[128 + t], i1 = si[128 + t];
        if (v1 < v0 || (v1 == v0 && i1 < i0)) { v0 = v1; i0 = i1; }
        pv [(size_t)ntile * N_TOK + row0 + t] = v0;
        pif[(size_t)ntile * N_TOK + row0 + t] = i0;
    }
}

// ---------------- outputs: fused 8-tile argmin + z_q, diff, ind -----------
__global__ __launch_bounds__(256) void vq_out_kernel(
    const float* __restrict__ z, const float* __restrict__ ew,
    const float* __restrict__ pv, const float* __restrict__ pif,
    float* __restrict__ indf, float* __restrict__ zq, float* __restrict__ diff) {
    const int w    = threadIdx.x >> 6;
    const int lane = threadIdx.x & 63;
    const int row  = blockIdx.x * 4 + w;

    // reduce the 8 n-tile partials (ascending -> first-min semantics)
    float v = INFINITY, ix = 0.f;
    if (lane < 8) {
        v  = pv [(size_t)lane * N_TOK + row];
        ix = pif[(size_t)lane * N_TOK + row];
    }
#pragma unroll
    for (int off = 1; off < 8; off <<= 1) {
        float v2 = __shfl_xor(v, off, 64);
        float i2 = __shfl_xor(ix, off, 64);
        if (v2 < v || (v2 == v && i2 < ix)) { v = v2; ix = i2; }
    }
    const float ixb = __shfl(ix, 0, 64);
    const int c = (int)ixb;
    if (lane == 0) indf[row] = ixb;

    const float4* z4 = (const float4*)&z[(size_t)row * D_DIM];
    const float4* e4 = (const float4*)&ew[(size_t)c * D_DIM];
    float4* q4 = (float4*)&zq[(size_t)row * D_DIM];
    float4* d4 = (float4*)&diff[(size_t)row * D_DIM];

#pragma unroll
    for (int vv = 0; vv < 2; ++vv) {
        const int i = vv * 64 + lane;
        const float4 zv = z4[i];
        const float4 ev = e4[i];
        float4 qv, dv;
        float ax = ev.x - zv.x, ay = ev.y - zv.y, az = ev.z - zv.z, aw = ev.w - zv.w;
        qv.x = zv.x + ax; qv.y = zv.y + ay; qv.z = zv.z + az; qv.w = zv.w + aw;
        dv.x = 0.5f * (ax * ax); dv.y = 0.5f * (ay * ay);
        dv.z = 0.5f * (az * az); dv.w = 0.5f * (aw * aw);
        q4[i] = qv;
        d4[i] = dv;
    }
}

extern "C" void kernel_launch(void* const* d_in, const int* in_sizes, int n_in,
                              void* d_out, int out_size, void* d_ws, size_t ws_size,
                              hipStream_t stream) {
    const float* z  = (const float*)d_in[0];
    const float* ew = (const float*)d_in[1];
    float* out  = (float*)d_out;
    float* zq   = out;
    float* diff = out + (size_t)N_TOK * D_DIM;
    float* indf = out + (size_t)2 * N_TOK * D_DIM;

    // scratch: ehi/elo/e2 in zq region (gemm reads them; out-kernel writes zq
    // only after); zhi/zlo in diff region; pv/pif in d_ws.
    char* s0 = (char*)d_out;
    unsigned short* ehi = (unsigned short*)(s0);                   // 1 MB
    unsigned short* elo = (unsigned short*)(s0 + (1u << 20));      // 1 MB
    float* e2  = (float*)(s0 + (2u << 20));                        // 4 KB
    unsigned short* zhi = (unsigned short*)diff;                   // 32 MB
    unsigned short* zlo = zhi + (size_t)N_TOK * D_DIM;             // 32 MB
    float* pv  = (float*)d_ws;                                     // 1 MB
    float* pif = (float*)d_ws + (size_t)8 * N_TOK;                 // 1 MB

    hipLaunchKernelGGL(vq_zsplit, dim3(2048),        dim3(256), 0, stream, z, zhi, zlo);
    hipLaunchKernelGGL(vq_prep,   dim3(K_CODES / 4), dim3(256), 0, stream, ew, ehi, elo, e2);
    hipLaunchKernelGGL(vq_gemm,   dim3(2048),        dim3(256), 0, stream,
                       zhi, zlo, ehi, elo, e2, pv, pif);
    hipLaunchKernelGGL(vq_out_kernel, dim3(N_TOK / 4), dim3(256), 0, stream,
                       z, ew, pv, pif, indf, zq, diff);
}

// Round 14
// 240.488 us; speedup vs baseline: 1.1194x; 1.0491x over previous
//
#include <hip/hip_runtime.h>
#include <math.h>

// VQ-VAE quantize: z [8,4096,512] f32, embed_w [1024,512] f32
// out = concat(z_q, diff, ind-as-f32)
//
// Strategy: 1-term fp16 MFMA approx scores + CERTIFIED exact refine.
//   s~ = ||e||^2 - 2*(z16 . e16)   (fp32 MFMA accum)
//   |s - s~| <= tau = 2(||z-z16||*maxE + ||z||*maxEl) + margin  (numerical norms)
//   gemm keeps lexicographic top-2 per (row, 128-code ntile); refine proves
//   the argmin from the window w = min + 2*tau, exact fp32 dots as needed.
// gemm skeleton = r6 (proven): gload_lds dbuf, counted vmcnt(8), setprio.

#define D_DIM   512
#define K_CODES 1024
#define N_TOK   32768

#define BM 128
#define BN 128
#define NKT 8             // 512 / 64 f16-cols per k-tile
#define BUFU 16384        // ushorts per LDS buffer (32 KB): A 16KB | B 16KB

typedef __attribute__((ext_vector_type(8))) _Float16 f16x8;
typedef __attribute__((ext_vector_type(4))) float f32x4;

#define GLOAD16(gp, lp)                                                        \
    __builtin_amdgcn_global_load_lds(                                          \
        (const __attribute__((address_space(1))) void*)(gp),                   \
        (__attribute__((address_space(3))) void*)(lp), 16, 0, 0)

#define SB0 __builtin_amdgcn_sched_barrier(0)

__device__ __forceinline__ bool lexlt(float v, float i, float w, float j) {
    return v < w || (v == w && i < j);
}
// merge two lex-sorted top-2 pairs -> top-2 of union
__device__ __forceinline__ void top2_merge(float& v1, float& i1, float& v2, float& i2,
                                           float w1, float j1, float w2, float j2) {
    const bool bf = lexlt(w1, j1, v1, i1);
    const float nv1 = bf ? w1 : v1, ni1 = bf ? j1 : i1;
    const bool s = bf ? lexlt(v1, i1, w2, j2) : lexlt(w1, j1, v2, i2);
    const float nv2 = bf ? (s ? v1 : w2) : (s ? w1 : v2);
    const float ni2 = bf ? (s ? i1 : j2) : (s ? j1 : i2);
    v1 = nv1; i1 = ni1; v2 = nv2; i2 = ni2;
}

// ---------------- rows -> f16 plane + ||x||^2 + ||x - f16(x)||^2 ----------
__global__ __launch_bounds__(256) void vq_cvt16(const float* __restrict__ src,
                                                _Float16* __restrict__ dst16,
                                                float* __restrict__ n2,
                                                float* __restrict__ r2o) {
    const int wv = threadIdx.x >> 6, lane = threadIdx.x & 63;
    const int row = blockIdx.x * 4 + wv;
    const float* rp = src + (size_t)row * D_DIM + lane * 8;
    float4 a = *(const float4*)rp;
    float4 b = *(const float4*)(rp + 4);
    float s2 = 0.f, r2 = 0.f;
    f16x8 h8;
#pragma unroll
    for (int j = 0; j < 8; ++j) {
        const float x = j < 4 ? (&a.x)[j] : (&b.x)[j - 4];
        const _Float16 h = (_Float16)x;
        const float r = x - (float)h;
        s2 = fmaf(x, x, s2);
        r2 = fmaf(r, r, r2);
        h8[j] = h;
    }
    *(f16x8*)(dst16 + (size_t)row * D_DIM + lane * 8) = h8;
#pragma unroll
    for (int off = 32; off > 0; off >>= 1) {
        s2 += __shfl_xor(s2, off, 64);
        r2 += __shfl_xor(r2, off, 64);
    }
    if (lane == 0) { n2[row] = s2; r2o[row] = r2; }
}

// ---------------- maxE = max ||e||, maxEl = max ||e-e16|| -----------------
__global__ __launch_bounds__(256) void vq_maxes(const float* __restrict__ e2,
                                                const float* __restrict__ el2,
                                                float* __restrict__ maxs) {
    const int t = threadIdx.x, wv = t >> 6, lane = t & 63;
    float mE = 0.f, mEl = 0.f;
#pragma unroll
    for (int q = 0; q < 4; ++q) {
        const int c = q * 256 + t;
        mE  = fmaxf(mE,  sqrtf(e2[c]));
        mEl = fmaxf(mEl, sqrtf(el2[c]));
    }
#pragma unroll
    for (int off = 32; off > 0; off >>= 1) {
        mE  = fmaxf(mE,  __shfl_xor(mE,  off, 64));
        mEl = fmaxf(mEl, __shfl_xor(mEl, off, 64));
    }
    __shared__ float red[8];
    if (lane == 0) { red[wv] = mE; red[4 + wv] = mEl; }
    __syncthreads();
    if (t == 0) {
        maxs[0] = fmaxf(fmaxf(red[0], red[1]), fmaxf(red[2], red[3]));
        maxs[1] = fmaxf(fmaxf(red[4], red[5]), fmaxf(red[6], red[7]));
    }
}

// ---------------- fp16 approx GEMM + per-ntile top-2 ----------------------
__global__ __launch_bounds__(256, 2) void vq_gemm16(
    const _Float16* __restrict__ z16, const _Float16* __restrict__ e16,
    const float* __restrict__ e2, float4* __restrict__ cand) {
    // 2 buffers x 32 KB; per buffer: A [8 kchunk][128 row]x16B, B same at +8192
    __shared__ __align__(16) unsigned short lds[2 * BUFU];

    const int t = threadIdx.x, lane = t & 63, wv = t >> 6;
    // XCD-contiguous swizzle: 2048 wgs, 8 XCDs, 256 each; ntile innermost
    const int b  = blockIdx.x;
    const int wg = (b & 7) * 256 + (b >> 3);
    const int mtile = wg >> 3, ntile = wg & 7;
    const int row0 = mtile * BM;
    const int c0g  = ntile * BN;

    // staging: slot s=q*256+t -> kchunk=q*2+(t>>7), row=t&127 ; 4 gloads/plane
    const int arow = t & 127, khalf = t >> 7;
    const size_t zob = (size_t)(row0 + arow) * D_DIM + khalf * 8;
    const size_t eob = (size_t)(c0g + arow) * D_DIM + khalf * 8;

    const int wr = wv >> 1, wc = wv & 1;
    const int lm = lane & 15, lk = lane >> 4;

    f32x4 acc[4][4];
    const f32x4 zero4 = {0.f, 0.f, 0.f, 0.f};
#pragma unroll
    for (int i = 0; i < 4; ++i)
#pragma unroll
        for (int j = 0; j < 4; ++j) acc[i][j] = zero4;

    auto stage = [&](int kt, int bufo) {
        const int ko = kt * 64;
#pragma unroll
        for (int q = 0; q < 4; ++q) {
            const int sl = (q * 256 + t) * 8;
            GLOAD16(z16 + zob + ko + q * 16, &lds[bufo + sl]);
            GLOAD16(e16 + eob + ko + q * 16, &lds[bufo + 8192 + sl]);
        }
    };

    auto compute = [&](int bufo) {
#pragma unroll
        for (int ks = 0; ks < 2; ++ks) {
            f16x8 af[4], bf[4];
#pragma unroll
            for (int mi = 0; mi < 4; ++mi)
                af[mi] = *(const f16x8*)&lds[bufo + ((ks * 4 + lk) * 128 + wr * 64 + mi * 16 + lm) * 8];
#pragma unroll
            for (int nj = 0; nj < 4; ++nj)
                bf[nj] = *(const f16x8*)&lds[bufo + 8192 + ((ks * 4 + lk) * 128 + wc * 64 + nj * 16 + lm) * 8];
            __builtin_amdgcn_s_setprio(1);
#pragma unroll
            for (int mi = 0; mi < 4; ++mi)
#pragma unroll
                for (int nj = 0; nj < 4; ++nj)
                    acc[mi][nj] = __builtin_amdgcn_mfma_f32_16x16x32_f16(
                        af[mi], bf[nj], acc[mi][nj], 0, 0, 0);
            __builtin_amdgcn_s_setprio(0);
        }
    };

    stage(0, 0);
    stage(1, BUFU);
    for (int kt = 0; kt < NKT - 1; ++kt) {
        const int bufo = (kt & 1) * BUFU;
        asm volatile("s_waitcnt vmcnt(8)" ::: "memory");   // this tile landed
        __builtin_amdgcn_s_barrier();
        SB0;
        compute(bufo);
        SB0;
        __builtin_amdgcn_s_barrier();                      // reads of bufo done
        if (kt + 2 < NKT) stage(kt + 2, bufo);
    }
    {
        const int bufo = ((NKT - 1) & 1) * BUFU;
        asm volatile("s_waitcnt vmcnt(0)" ::: "memory");
        __builtin_amdgcn_s_barrier();
        SB0;
        compute(bufo);
    }

    // ---- epilogue: per-row lexicographic top-2 over this 128-code tile ----
    // D mapping (16x16x32): col=lane&15 (code), row=(lane>>4)*4+reg (z-row)
    float e2v[4], cif[4];
#pragma unroll
    for (int nj = 0; nj < 4; ++nj) {
        const int cloc = wc * 64 + nj * 16 + lm;
        e2v[nj] = e2[c0g + cloc];
        cif[nj] = (float)(c0g + cloc);
    }
    __syncthreads();                 // all waves done with GEMM LDS
    float* svv = (float*)lds;        // [2][128][4]
#pragma unroll
    for (int mi = 0; mi < 4; ++mi) {
#pragma unroll
        for (int r = 0; r < 4; ++r) {
            float v1 = INFINITY, i1 = INFINITY, v2 = INFINITY, i2 = INFINITY;
#pragma unroll
            for (int nj = 0; nj < 4; ++nj) {
                const float v = fmaf(-2.0f, acc[mi][nj][r], e2v[nj]);
                const float ci = cif[nj];
                if (lexlt(v, ci, v1, i1)) { v2 = v1; i2 = i1; v1 = v; i1 = ci; }
                else if (lexlt(v, ci, v2, i2)) { v2 = v; i2 = ci; }
            }
#pragma unroll
            for (int off = 1; off < 16; off <<= 1) {
                const float w1 = __shfl_xor(v1, off, 64), j1 = __shfl_xor(i1, off, 64);
                const float w2 = __shfl_xor(v2, off, 64), j2 = __shfl_xor(i2, off, 64);
                top2_merge(v1, i1, v2, i2, w1, j1, w2, j2);
            }
            if (lm == 0) {
                const int rl = wr * 64 + mi * 16 + lk * 4 + r;
                float* p = &svv[(wc * 128 + rl) * 4];
                p[0] = v1; p[1] = i1; p[2] = v2; p[3] = i2;
            }
        }
    }
    __syncthreads();
    if (t < 128) {
        const float* pa = &svv[t * 4];
        const float* pb = &svv[(128 + t) * 4];
        float v1 = pa[0], i1 = pa[1], v2 = pa[2], i2 = pa[3];
        top2_merge(v1, i1, v2, i2, pb[0], pb[1], pb[2], pb[3]);
        cand[(size_t)ntile * N_TOK + row0 + t] = make_float4(v1, i1, v2, i2);
    }
}

// ---------------- certified refine -> final indices -----------------------
__global__ __launch_bounds__(256) void vq_refine(
    const float4* __restrict__ cand, const float* __restrict__ z,
    const float* __restrict__ ew, const float* __restrict__ e2,
    const float* __restrict__ z2, const float* __restrict__ zl2,
    const float* __restrict__ maxs, float* __restrict__ indf) {
    const int wv = threadIdx.x >> 6, lane = threadIdx.x & 63;
    const int row = blockIdx.x * 4 + wv;

    float v1 = INFINITY, i1 = INFINITY, v2 = INFINITY, i2 = INFINITY;
    if (lane < 8) {
        const float4 cd = cand[(size_t)lane * N_TOK + row];
        v1 = cd.x; i1 = cd.y; v2 = cd.z; i2 = cd.w;
    }
    // global lex-min over the 8 v1's
    float mv = v1, mi_ = i1;
#pragma unroll
    for (int off = 1; off < 64; off <<= 1) {
        const float ov = __shfl_xor(mv, off, 64), oi = __shfl_xor(mi_, off, 64);
        if (lexlt(ov, oi, mv, mi_)) { mv = ov; mi_ = oi; }
    }
    const float tau = 2.0f * (sqrtf(zl2[row]) * maxs[0]
                              + 1.001f * sqrtf(z2[row]) * maxs[1]) + 0.25f;
    const float w = mv + 2.0f * tau;

    const unsigned long long m1 = __ballot((lane < 8) && (v1 <= w));
    const unsigned long long m2 = __ballot((lane < 8) && (v2 <= w));
    if (m2 == 0 && __popcll(m1) == 1) {
        if (lane == 0) indf[row] = mi_;    // unique certified winner
        return;
    }

    // slow path: exact fp32 scores for window candidates (+ full rescan of
    // any ntile whose 2nd-best is inside the window -> hidden-3rd certificate)
    const float* zp = z + (size_t)row * D_DIM + lane * 8;
    const float4 za = *(const float4*)zp;
    const float4 zb = *(const float4*)(zp + 4);
    float bs = INFINITY, bi = INFINITY;

    auto evalc = [&](int c) {
        const float* ep = ew + (size_t)c * D_DIM + lane * 8;
        const float4 ea = *(const float4*)ep;
        const float4 eb = *(const float4*)(ep + 4);
        float d = 0.f;
        d = fmaf(za.x, ea.x, d); d = fmaf(za.y, ea.y, d);
        d = fmaf(za.z, ea.z, d); d = fmaf(za.w, ea.w, d);
        d = fmaf(zb.x, eb.x, d); d = fmaf(zb.y, eb.y, d);
        d = fmaf(zb.z, eb.z, d); d = fmaf(zb.w, eb.w, d);
#pragma unroll
        for (int off = 1; off < 64; off <<= 1) d += __shfl_xor(d, off, 64);
        const float s = fmaf(-2.0f, d, e2[c]);
        const float ci = (float)c;
        if (lexlt(s, ci, bs, bi)) { bs = s; bi = ci; }
    };

    for (int j = 0; j < 8; ++j) {
        const float v2j = __shfl(v2, j, 64);
        if (v2j <= w) {                       // rescan whole ntile j
            for (int c = j * 128; c < j * 128 + 128; ++c) evalc(c);
        } else {
            const float v1j = __shfl(v1, j, 64);
            if (v1j <= w) evalc((int)__shfl(i1, j, 64));
        }
    }
    if (lane == 0) indf[row] = bi;
}

// ---------------- outputs: z_q, diff --------------------------------------
__global__ __launch_bounds__(256) void vq_out_kernel(
    const float* __restrict__ z, const float* __restrict__ ew,
    const float* __restrict__ indf, float* __restrict__ zq,
    float* __restrict__ diff) {
    const int w    = threadIdx.x >> 6;
    const int lane = threadIdx.x & 63;
    const int row  = blockIdx.x * 4 + w;
    const int c    = (int)indf[row];

    const float4* z4 = (const float4*)&z[(size_t)row * D_DIM];
    const float4* e4 = (const float4*)&ew[(size_t)c * D_DIM];
    float4* q4 = (float4*)&zq[(size_t)row * D_DIM];
    float4* d4 = (float4*)&diff[(size_t)row * D_DIM];

#pragma unroll
    for (int vv = 0; vv < 2; ++vv) {
        const int i = vv * 64 + lane;
        const float4 zv = z4[i];
        const float4 ev = e4[i];
        float4 qv, dv;
        float ax = ev.x - zv.x, ay = ev.y - zv.y, az = ev.z - zv.z, aw = ev.w - zv.w;
        qv.x = zv.x + ax; qv.y = zv.y + ay; qv.z = zv.z + az; qv.w = zv.w + aw;
        dv.x = 0.5f * (ax * ax); dv.y = 0.5f * (ay * ay);
        dv.z = 0.5f * (az * az); dv.w = 0.5f * (aw * aw);
        q4[i] = qv;
        d4[i] = dv;
    }
}

extern "C" void kernel_launch(void* const* d_in, const int* in_sizes, int n_in,
                              void* d_out, int out_size, void* d_ws, size_t ws_size,
                              hipStream_t stream) {
    const float* z  = (const float*)d_in[0];
    const float* ew = (const float*)d_in[1];
    float* out  = (float*)d_out;
    float* zq   = out;
    float* diff = out + (size_t)N_TOK * D_DIM;
    float* indf = out + (size_t)2 * N_TOK * D_DIM;   // real output; refine writes

    // scratch in zq region (read before out-kernel overwrites it):
    char* s0 = (char*)d_out;
    _Float16* e16 = (_Float16*)s0;                         // 1 MB
    float* e2   = (float*)(s0 + (1u << 20));               // 4 KB
    float* el2  = (float*)(s0 + (1u << 20) + 4096);        // 4 KB
    float* z2   = (float*)(s0 + (1u << 20) + 8192);        // 128 KB
    float* zl2  = (float*)(s0 + (1u << 20) + 8192 + 131072);     // 128 KB
    float* maxs = (float*)(s0 + (1u << 20) + 8192 + 262144);     // 8 B
    float4* cand = (float4*)(s0 + (2u << 20));             // 4 MB
    _Float16* z16 = (_Float16*)diff;                       // 32 MB (diff region)

    hipLaunchKernelGGL(vq_cvt16, dim3(N_TOK / 4),   dim3(256), 0, stream, z, z16, z2, zl2);
    hipLaunchKernelGGL(vq_cvt16, dim3(K_CODES / 4), dim3(256), 0, stream, ew, e16, e2, el2);
    hipLaunchKernelGGL(vq_maxes, dim3(1),           dim3(256), 0, stream, e2, el2, maxs);
    hipLaunchKernelGGL(vq_gemm16, dim3(2048),       dim3(256), 0, stream, z16, e16, e2, cand);
    hipLaunchKernelGGL(vq_refine, dim3(N_TOK / 4),  dim3(256), 0, stream,
                       cand, z, ew, e2, z2, zl2, maxs, indf);
    hipLaunchKernelGGL(vq_out_kernel, dim3(N_TOK / 4), dim3(256), 0, stream,
                       z, ew, indf, zq, diff);
}